// Round 6
// baseline (37.414 us; speedup 1.0000x reference)
//
#include <hip/hip_runtime.h>
#include <math.h>

// x: (B=2048, S=1024, D=12) f32. K = select_num = VOTE_PERHEAD = 24. S = 32*32.
// 512 blocks x 256 threads; each block processes 4 consecutive rows,
// software-pipelined: load row j+1 while processing row j (1 DRAM stream/block).
constexpr int S_  = 1024;
constexpr int D_  = 12;
constexpr int K_  = 24;
constexpr int NT  = 256;
constexpr int RPB = 4;
constexpr int NL  = 5;

__device__ __forceinline__ void stamp3x3(int p, unsigned int* convp) {
    int r = p >> 5, c0 = p & 31;
    #pragma unroll
    for (int dr = -1; dr <= 1; ++dr) {
        int rr = r + dr;
        if (rr < 0 || rr >= 32) continue;
        #pragma unroll
        for (int dc = -1; dc <= 1; ++dc) {
            int cc = c0 + dc;
            if (cc < 0 || cc >= 32) continue;
            unsigned int w = ((dr == 0) ? 2u : 1u) * ((dc == 0) ? 2u : 1u);
            int q = rr * 32 + cc;
            atomicAdd(&convp[q >> 2], w << ((q & 3) * 8)); // packed u8, max 16
        }
    }
}

__global__ __launch_bounds__(NT) void mhv_kernel(const float* __restrict__ x,
                                                 float* __restrict__ out_idx,  // B*K
                                                 float* __restrict__ out_cnt,  // B*S
                                                 int B)
{
    const int tid  = threadIdx.x;
    const int lane = tid & 63;
    const int wid  = tid >> 6;
    const int r0   = blockIdx.x * RPB;

    __shared__ unsigned int       convp[S_ / 4];  // packed 4x u8 conv counts
    __shared__ unsigned long long slab[256];      // candidate keys (c <= 256)
    __shared__ int                ck[112];        // count>=4 cells (c2 <= 96)
    __shared__ int                wcnt[4][NL];    // per-wave ladder counts
    __shared__ int                nc[RPB], nck[RPB];

    if (tid < RPB) { nc[tid] = 0; nck[tid] = 0; }

    const float LAD[NL] = {2.6f, 2.2f, 1.9f, 1.6f, 1.3f};

    float v0[4], v1[4], v2[4], v3[4];

    auto LOADR = [&](float (&v)[4], int row) {
        const float* xr = x + (size_t)row * (S_ * D_);
        #pragma unroll
        for (int i = 0; i < 4; ++i) {
            int s = i * 256 + tid;                 // lane-consecutive -> 48B stride
            v[i] = (s < S_ - 1) ? xr[(s + 1) * D_] : -INFINITY;
        }
    };

    auto PROCESS = [&](float (&v)[4], int jrow, int row) {
        convp[tid] = 0u;                           // pre-B1 (prev readers done: B4)
        slab[tid]  = 0ull;
        // ladder counts directly on floats (rungs > 0 => same order as bits)
        #pragma unroll
        for (int r = 0; r < NL; ++r) {
            int c = 0;
            #pragma unroll
            for (int i = 0; i < 4; ++i) c += __popcll(__ballot(v[i] >= LAD[r]));
            if (lane == 0) wcnt[wid][r] = c;
        }
        __syncthreads();                           // B1
        if (tid < 112) ck[tid] = -1;               // post-B1: prev rank2 finished
        // rung select (block-uniform): first rung with count >= K
        int csel = -1; float Lsel = 0.f;
        #pragma unroll
        for (int r = 0; r < NL; ++r) {
            int ct = wcnt[0][r] + wcnt[1][r] + wcnt[2][r] + wcnt[3][r];
            if (csel < K_ && ct >= K_) { csel = ct; Lsel = LAD[r]; }
        }

        if (csel >= K_ && csel <= 256) {
            // ---- compact candidates (key: value desc, index asc) ----
            #pragma unroll
            for (int i = 0; i < 4; ++i) {
                int s = i * 256 + tid;
                bool sel = (v[i] >= Lsel);
                unsigned long long m = __ballot(sel);
                int cnt = __popcll(m);
                int base = 0;
                if (lane == 0) base = atomicAdd(&nc[jrow], cnt);
                base = __shfl(base, 0);
                if (sel) {
                    unsigned int su = __float_as_uint(v[i]) | 0x80000000u; // v > 0
                    slab[base + __popcll(m & ((1ull << lane) - 1ull))] =
                        ((unsigned long long)su << 10) | (unsigned)(S_ - 1 - s);
                }
            }
            __syncthreads();                       // B2
            int c = nc[jrow];
            if (tid < c) {
                unsigned long long kk = slab[tid];
                int rk = 0;
                for (int j = 0; j < c; j += 4) {
                    #pragma unroll
                    for (int u = 0; u < 4; ++u)
                        if (j + u < c) rk += (slab[j + u] > kk);
                }
                if (rk < K_) stamp3x3(S_ - 1 - (int)(kk & 1023ull), convp);
            }
            __syncthreads();                       // B3
        } else {
            // ---- rare exact fallback: per-wave 42-bit ballot search ----
            unsigned long long k64[4];
            #pragma unroll
            for (int i = 0; i < 4; ++i) {
                int s = i * 256 + tid;
                unsigned int bits = __float_as_uint(v[i]);   // -inf ok (maps low)
                unsigned int su = (bits & 0x80000000u) ? ~bits : (bits | 0x80000000u);
                k64[i] = ((unsigned long long)su << 10) | (unsigned)(S_ - 1 - s);
            }
            unsigned long long t = 0ull;
            for (int bit = 41; bit >= 0; --bit) {
                unsigned long long tr = t | (1ull << bit);
                int c = 0;
                #pragma unroll
                for (int i = 0; i < 4; ++i) c += __popcll(__ballot(k64[i] >= tr));
                if (c >= K_) t = tr;
            }
            int base = wid * K_;                   // exactly 24 per wave (unique keys)
            #pragma unroll
            for (int i = 0; i < 4; ++i) {
                bool sel = (k64[i] >= t);
                unsigned long long m = __ballot(sel);
                if (sel) slab[base + __popcll(m & ((1ull << lane) - 1ull))] = k64[i];
                base += __popcll(m);
            }
            __syncthreads();                       // B2
            if (wid == 0) {
                unsigned long long g0 = slab[lane];
                unsigned long long g1 = (lane < 32) ? slab[64 + lane] : 0ull;
                unsigned long long t2 = 0ull;
                for (int bit = 41; bit >= 0; --bit) {
                    unsigned long long tr = t2 | (1ull << bit);
                    int c = __popcll(__ballot(g0 >= tr)) + __popcll(__ballot(g1 >= tr));
                    if (c >= K_) t2 = tr;
                }
                if (g0 >= t2) stamp3x3(S_ - 1 - (int)(g0 & 1023ull), convp);
                if (lane < 32 && g1 >= t2) stamp3x3(S_ - 1 - (int)(g1 & 1023ull), convp);
            }
            __syncthreads();                       // B3
        }

        // ---- unpack conv, write output 1, compact count>=4 cells ----
        unsigned int pd = convp[tid];
        float4 o;
        o.x = (float)(pd & 255u);
        o.y = (float)((pd >> 8) & 255u);
        o.z = (float)((pd >> 16) & 255u);
        o.w = (float)(pd >> 24);
        *(float4*)(out_cnt + (size_t)row * S_ + tid * 4) = o;
        #pragma unroll
        for (int q = 0; q < 4; ++q) {
            unsigned int cv = (pd >> (q * 8)) & 255u;
            bool sel = (cv >= 4u);                 // 24 centers have >=4 => superset
            unsigned long long m = __ballot(sel);
            int cnt = __popcll(m);
            int base = 0;
            if (lane == 0) base = atomicAdd(&nck[jrow], cnt);
            base = __shfl(base, 0);
            if (sel) {
                int p = tid * 4 + q;
                ck[base + __popcll(m & ((1ull << lane) - 1ull))] =
                    (int)(cv << 10) | (S_ - 1 - p); // count desc, index asc
            }
        }
        __syncthreads();                           // B4
        int c2 = nck[jrow];                        // 24 <= c2 <= 96
        if (tid < c2) {
            int kk = ck[tid];
            int rk = 0;
            for (int j = 0; j < c2; j += 4) {
                #pragma unroll
                for (int u = 0; u < 4; ++u)
                    if (j + u < c2) rk += (ck[j + u] > kk);
            }
            if (rk < K_)
                out_idx[(size_t)row * K_ + rk] = (float)(S_ - (kk & 1023)); // p+1
        }
    };

    const bool has1 = (r0 + 1 < B), has2 = (r0 + 2 < B), has3 = (r0 + 3 < B);

    LOADR(v0, r0);
    if (has1) LOADR(v1, r0 + 1);
    PROCESS(v0, 0, r0);
    __builtin_amdgcn_sched_barrier(0);
    if (has2) LOADR(v2, r0 + 2);
    if (has1) PROCESS(v1, 1, r0 + 1);
    __builtin_amdgcn_sched_barrier(0);
    if (has3) LOADR(v3, r0 + 3);
    if (has2) PROCESS(v2, 2, r0 + 2);
    if (has3) PROCESS(v3, 3, r0 + 3);
}

extern "C" void kernel_launch(void* const* d_in, const int* in_sizes, int n_in,
                              void* d_out, int out_size, void* d_ws, size_t ws_size,
                              hipStream_t stream) {
    const float* x = (const float*)d_in[0];
    const int B = in_sizes[0] / (S_ * D_);

    float* out     = (float*)d_out;
    float* out_idx = out;                    // B*K_ (patch_idx, 1-based, as f32)
    float* out_cnt = out + (size_t)B * K_;   // B*S_ (count)

    int blocks = (B + RPB - 1) / RPB;
    mhv_kernel<<<dim3(blocks), dim3(NT), 0, stream>>>(x, out_idx, out_cnt, B);
}

// Round 7
// 27.298 us; speedup vs baseline: 1.3706x; 1.3706x over previous
//
#include <hip/hip_runtime.h>
#include <math.h>

// x: (B=2048, S=1024, D=12) f32. K = select_num = VOTE_PERHEAD = 24. S = 32*32.
// One 256-thread block per row. Dense float4 row read; score column extracted
// in registers (score s = x4[3*(s+1)].x). Selection pipeline identical to R4.
constexpr int S_ = 1024;
constexpr int D_ = 12;
constexpr int K_ = 24;
constexpr int NT = 256;
constexpr int NL = 5;

__device__ __forceinline__ void stamp3x3(int p, unsigned int* convp) {
    int r = p >> 5, c0 = p & 31;
    #pragma unroll
    for (int dr = -1; dr <= 1; ++dr) {
        int rr = r + dr;
        if (rr < 0 || rr >= 32) continue;
        #pragma unroll
        for (int dc = -1; dc <= 1; ++dc) {
            int cc = c0 + dc;
            if (cc < 0 || cc >= 32) continue;
            unsigned int w = ((dr == 0) ? 2u : 1u) * ((dc == 0) ? 2u : 1u);
            int q = rr * 32 + cc;
            atomicAdd(&convp[q >> 2], w << ((q & 3) * 8));  // packed u8, max 16
        }
    }
}

__global__ __launch_bounds__(NT) void mhv_kernel(const float* __restrict__ x,
                                                 float* __restrict__ out_idx,  // B*K
                                                 float* __restrict__ out_cnt)  // B*S
{
    const int b    = blockIdx.x;
    const int tid  = threadIdx.x;
    const int lane = tid & 63;
    const int wid  = tid >> 6;

    __shared__ unsigned int       convp[S_ / 4];  // packed 4x u8 conv counts
    __shared__ unsigned long long slab[256];      // candidates (main) / 96 (fallback)
    __shared__ int                ck[112];        // count>=4 cells (24..96)
    __shared__ int                wcnt[4][NL];
    __shared__ int                ncand, nck;

    convp[tid] = 0u;
    if (tid == 0) { ncand = 0; nck = 0; }

    // ---- dense coalesced row read; extract score column in registers ----
    const float4* x4 = (const float4*)(x + (size_t)b * (S_ * D_));
    const int r    = (3 - tid % 3) % 3;     // qualifying i within each 3-load chunk
    const int q    = (r * 256 + tid) / 3;   // exact (r*256+tid ≡ 0 mod 3)
    float v[4];                              // v[c] = score s = c*256 + q - 1
    #pragma unroll
    for (int c = 0; c < 4; ++c) {
        float4 a  = x4[c * 768 +        tid];
        float4 bb = x4[c * 768 + 256  + tid];
        float4 cc = x4[c * 768 + 512  + tid];
        v[c] = (r == 0) ? a.x : ((r == 1) ? bb.x : cc.x);
    }
    if (tid == 0) v[0] = -INFINITY;          // dummy slot (s = -1)

    // ---- threshold ladder; per-wave counts -> LDS ----
    const float LAD[NL] = {2.6f, 2.2f, 1.9f, 1.6f, 1.3f};
    #pragma unroll
    for (int j = 0; j < NL; ++j) {
        int c = 0;
        #pragma unroll
        for (int i = 0; i < 4; ++i) c += __popcll(__ballot(v[i] >= LAD[j]));
        if (lane == 0) wcnt[wid][j] = c;
    }
    __syncthreads();                         // B1

    int csel = -1; float Lsel = 0.f;
    #pragma unroll
    for (int j = 0; j < NL; ++j) {
        int ct = wcnt[0][j] + wcnt[1][j] + wcnt[2][j] + wcnt[3][j];
        if (csel < K_ && ct >= K_) { csel = ct; Lsel = LAD[j]; }
    }

    if (csel >= K_ && csel <= 256) {
        // ---- compact candidates (key: value desc, index asc) ----
        #pragma unroll
        for (int i = 0; i < 4; ++i) {
            int s = i * 256 + q - 1;
            bool sel = (v[i] >= Lsel);       // dummy is -inf: never selected
            unsigned long long m = __ballot(sel);
            int cnt = __popcll(m);
            int base = 0;
            if (lane == 0) base = atomicAdd(&ncand, cnt);
            base = __shfl(base, 0);
            if (sel) {
                unsigned int su = __float_as_uint(v[i]) | 0x80000000u;  // v > 0
                slab[base + __popcll(m & ((1ull << lane) - 1ull))] =
                    ((unsigned long long)su << 10) | (unsigned)(S_ - 1 - s);
            }
        }
        __syncthreads();                     // B2
        int c = ncand;
        if (tid < c) {
            unsigned long long kk = slab[tid];
            int rk = 0;
            for (int j = 0; j < c; j += 4) {
                #pragma unroll
                for (int u = 0; u < 4; ++u)
                    if (j + u < c) rk += (slab[j + u] > kk);
            }
            if (rk < K_) stamp3x3(S_ - 1 - (int)(kk & 1023ull), convp);
        }
        __syncthreads();                     // B3
    } else {
        // ---- rare exact fallback: per-wave 42-bit ballot search ----
        unsigned long long k64[4];
        #pragma unroll
        for (int i = 0; i < 4; ++i) {
            int s = i * 256 + q - 1;
            unsigned int bits = __float_as_uint(v[i]);
            unsigned int su = (bits & 0x80000000u) ? ~bits : (bits | 0x80000000u);
            k64[i] = (s >= 0)
                ? (((unsigned long long)su << 10) | (unsigned)(S_ - 1 - s))
                : 0ull;                      // dummy: minimal key
        }
        unsigned long long t = 0ull;
        for (int bit = 41; bit >= 0; --bit) {
            unsigned long long tr = t | (1ull << bit);
            int c = 0;
            #pragma unroll
            for (int i = 0; i < 4; ++i) c += __popcll(__ballot(k64[i] >= tr));
            if (c >= K_) t = tr;
        }
        int base = wid * K_;                 // exactly 24/wave (keys unique)
        #pragma unroll
        for (int i = 0; i < 4; ++i) {
            bool sel = (k64[i] >= t);
            unsigned long long m = __ballot(sel);
            if (sel) slab[base + __popcll(m & ((1ull << lane) - 1ull))] = k64[i];
            base += __popcll(m);
        }
        __syncthreads();                     // B2
        if (wid == 0) {
            unsigned long long g0 = slab[lane];
            unsigned long long g1 = (lane < 32) ? slab[64 + lane] : 0ull;
            unsigned long long t2 = 0ull;
            for (int bit = 41; bit >= 0; --bit) {
                unsigned long long tr = t2 | (1ull << bit);
                int c = __popcll(__ballot(g0 >= tr)) + __popcll(__ballot(g1 >= tr));
                if (c >= K_) t2 = tr;
            }
            if (g0 >= t2) stamp3x3(S_ - 1 - (int)(g0 & 1023ull), convp);
            if (lane < 32 && g1 >= t2) stamp3x3(S_ - 1 - (int)(g1 & 1023ull), convp);
        }
        __syncthreads();                     // B3
    }

    // ---- unpack conv, write output 1, compact count>=4 cells ----
    unsigned int pd = convp[tid];
    {
        float4 o;
        o.x = (float)(pd & 255u);
        o.y = (float)((pd >> 8) & 255u);
        o.z = (float)((pd >> 16) & 255u);
        o.w = (float)(pd >> 24);
        *(float4*)(out_cnt + (size_t)b * S_ + tid * 4) = o;
    }
    #pragma unroll
    for (int qq = 0; qq < 4; ++qq) {
        unsigned int cv = (pd >> (qq * 8)) & 255u;
        bool sel = (cv >= 4u);               // 24 centers have count>=4 => superset
        unsigned long long m = __ballot(sel);
        int cnt = __popcll(m);
        int base = 0;
        if (lane == 0) base = atomicAdd(&nck, cnt);
        base = __shfl(base, 0);
        if (sel) {
            int p = tid * 4 + qq;
            ck[base + __popcll(m & ((1ull << lane) - 1ull))] =
                (int)(cv << 10) | (S_ - 1 - p);  // count desc, index asc
        }
    }
    __syncthreads();                         // B4
    int c2 = nck;                            // 24 <= c2 <= 96
    if (tid < c2) {
        int kk = ck[tid];
        int rk = 0;
        for (int j = 0; j < c2; j += 4) {
            #pragma unroll
            for (int u = 0; u < 4; ++u)
                if (j + u < c2) rk += (ck[j + u] > kk);
        }
        if (rk < K_)
            out_idx[(size_t)b * K_ + rk] = (float)(S_ - (kk & 1023));  // p + 1
    }
}

extern "C" void kernel_launch(void* const* d_in, const int* in_sizes, int n_in,
                              void* d_out, int out_size, void* d_ws, size_t ws_size,
                              hipStream_t stream) {
    const float* x = (const float*)d_in[0];
    const int B = in_sizes[0] / (S_ * D_);

    float* out     = (float*)d_out;
    float* out_idx = out;                    // B*K_ (patch_idx, 1-based, as f32)
    float* out_cnt = out + (size_t)B * K_;   // B*S_ (count)

    mhv_kernel<<<dim3(B), dim3(NT), 0, stream>>>(x, out_idx, out_cnt);
}

// Round 8
// 25.232 us; speedup vs baseline: 1.4828x; 1.0818x over previous
//
#include <hip/hip_runtime.h>

// MultiHeadVoting — x: (B=2048, S=1024, D=12) f32, K = 24, S = 32*32.
//
// ROOFLINE NOTE: score s lives at float offset 12*s in a row; every 64B line
// of the 100.7 MB x tensor contains >=1 score (gap 48B < 64B), so line traffic
// is irreducible. Best measured 25.2 us = 4.03 TB/s sustained line-fill rate,
// invariant across scattered/dense/0-barrier/4-barrier designs — the per-CU
// outstanding-line-fill (Little's law) ceiling (~50 lines x 64B / ~480cy LLC
// latency x 256 CU ~= 4 TB/s). This file is the best-measured variant (R4).
constexpr int S_ = 1024;
constexpr int D_ = 12;
constexpr int K_ = 24;
constexpr int NT = 256;   // 4 waves; one block per batch row
constexpr int NL = 5;     // threshold-ladder rungs

// monotone-transformed (bits|0x80000000 for positive floats) ladder:
// {2.6f, 2.2f, 1.9f, 1.6f, 1.3f}
__constant__ const unsigned int U_LADDER[NL] =
    {0xC0266666u, 0xC00CCCCDu, 0xBFF33333u, 0xBFCCCCCDu, 0xBFA66666u};

__device__ __forceinline__ void stamp3x3(int p, unsigned int* convp) {
    int r = p >> 5, c0 = p & 31;
    #pragma unroll
    for (int dr = -1; dr <= 1; ++dr) {
        int rr = r + dr;
        if (rr < 0 || rr >= 32) continue;
        #pragma unroll
        for (int dc = -1; dc <= 1; ++dc) {
            int cc = c0 + dc;
            if (cc < 0 || cc >= 32) continue;
            unsigned int w = ((dr == 0) ? 2u : 1u) * ((dc == 0) ? 2u : 1u);
            int q = rr * 32 + cc;
            atomicAdd(&convp[q >> 2], w << ((q & 3) * 8));  // packed u8, max 16: no carry
        }
    }
}

__global__ __launch_bounds__(NT) void mhv_kernel(const float* __restrict__ x,
                                                 float* __restrict__ out_idx,  // B*K
                                                 float* __restrict__ out_cnt)  // B*S
{
    const int b    = blockIdx.x;
    const int tid  = threadIdx.x;
    const int lane = tid & 63;
    const int wid  = tid >> 6;

    __shared__ unsigned long long slab[S_];     // score candidate keys (worst case all)
    __shared__ unsigned int       convp[S_/4];  // packed 4x u8 conv counts
    __shared__ int                ck[96];       // count-candidates (count>=4): 24..96
    __shared__ int                wcnt[4][NL];  // per-wave ladder counts
    __shared__ int                ncand, nck;

    convp[tid] = 0u;
    if (tid == 0) { ncand = 0; nck = 0; }

    // ---- load 4 scores/thread, monotone key transform ----
    const float* xb = x + (size_t)b * (S_ * D_);
    unsigned int su[4];
    #pragma unroll
    for (int i = 0; i < 4; ++i) {
        int s = wid * 256 + i * 64 + lane;
        su[i] = 0u;                                // s==1023: no score (min key)
        if (s < S_ - 1) {
            unsigned int bits = __float_as_uint(xb[(s + 1) * D_]);
            su[i] = (bits & 0x80000000u) ? ~bits : (bits | 0x80000000u);
        }
    }

    // ---- ladder counts: 4 ballots per rung, lane0 posts wave totals ----
    int cw[NL];
    #pragma unroll
    for (int j = 0; j < NL; ++j) {
        int c = 0;
        #pragma unroll
        for (int i = 0; i < 4; ++i) c += __popcll(__ballot(su[i] >= U_LADDER[j]));
        cw[j] = c;
    }
    if (lane == 0) {
        #pragma unroll
        for (int j = 0; j < NL; ++j) wcnt[wid][j] = cw[j];
    }
    __syncthreads();

    // ---- choose tightest rung with block count >= K (fallback: all scores) ----
    int jsel = -1;
    #pragma unroll
    for (int j = 0; j < NL; ++j) {
        int ct = wcnt[0][j] + wcnt[1][j] + wcnt[2][j] + wcnt[3][j];
        if (jsel < 0 && ct >= K_) jsel = j;
    }
    unsigned int Usel = (jsel >= 0) ? U_LADDER[jsel] : 1u;   // su>=1 <=> real score

    // ---- compact candidate keys to LDS ----
    #pragma unroll
    for (int i = 0; i < 4; ++i) {
        bool sel = (su[i] >= Usel);
        unsigned long long m = __ballot(sel);
        int cnt = __popcll(m);
        int base = 0;
        if (lane == 0) base = atomicAdd(&ncand, cnt);
        base = __shfl(base, 0);
        if (sel) {
            int s = wid * 256 + i * 64 + lane;
            slab[base + __popcll(m & ((1ull << lane) - 1ull))] =
                ((unsigned long long)su[i] << 10) | (unsigned)(S_ - 1 - s);
        }
    }
    __syncthreads();

    // ---- exact rank among candidates; rank<24 stamps its 3x3 votes ----
    int c = ncand;                      // 24 <= c <= 1023, typically ~30
    if (c <= NT) {
        if (tid < c) {
            unsigned long long kk = slab[tid];
            int rk = 0;
            for (int j = 0; j < c; ++j) rk += (slab[j] > kk);
            if (rk < K_) stamp3x3(S_ - 1 - (int)(kk & 1023ull), convp);
        }
    } else {                            // cold fallback path, still exact
        unsigned long long kk0 = (tid          < c) ? slab[tid]          : 0ull;
        unsigned long long kk1 = (tid + NT     < c) ? slab[tid + NT]     : 0ull;
        unsigned long long kk2 = (tid + 2*NT   < c) ? slab[tid + 2*NT]   : 0ull;
        unsigned long long kk3 = (tid + 3*NT   < c) ? slab[tid + 3*NT]   : 0ull;
        int r0 = 0, r1 = 0, r2 = 0, r3 = 0;
        for (int j = 0; j < c; ++j) {
            unsigned long long kj = slab[j];
            r0 += (kj > kk0); r1 += (kj > kk1); r2 += (kj > kk2); r3 += (kj > kk3);
        }
        if (tid          < c && r0 < K_) stamp3x3(S_ - 1 - (int)(kk0 & 1023ull), convp);
        if (tid + NT     < c && r1 < K_) stamp3x3(S_ - 1 - (int)(kk1 & 1023ull), convp);
        if (tid + 2*NT   < c && r2 < K_) stamp3x3(S_ - 1 - (int)(kk2 & 1023ull), convp);
        if (tid + 3*NT   < c && r3 < K_) stamp3x3(S_ - 1 - (int)(kk3 & 1023ull), convp);
    }
    __syncthreads();

    // ---- unpack counts, write output 1, compact cells with count>=4 ----
    // Every vote center has count>=4 => 24 <= c2; mass 24*16=384 => c2 <= 96,
    // and the top-24-by-(count,idx) is a subset of {count>=4}. No search needed.
    unsigned int pw = convp[tid];
    {
        float4 o;
        o.x = (float)(pw & 255u);
        o.y = (float)((pw >> 8) & 255u);
        o.z = (float)((pw >> 16) & 255u);
        o.w = (float)(pw >> 24);
        *(float4*)(out_cnt + (size_t)b * S_ + tid * 4) = o;
    }
    #pragma unroll
    for (int jj = 0; jj < 4; ++jj) {
        unsigned int cv = (pw >> (jj * 8)) & 255u;
        bool sel = (cv >= 4u);
        unsigned long long m = __ballot(sel);
        int cnt = __popcll(m);
        int base = 0;
        if (lane == 0) base = atomicAdd(&nck, cnt);
        base = __shfl(base, 0);
        if (sel) {
            int p = tid * 4 + jj;
            ck[base + __popcll(m & ((1ull << lane) - 1ull))] =
                (int)(cv << 10) | (S_ - 1 - p);        // count desc, index asc
        }
    }
    __syncthreads();

    // ---- exact stable rank; ranks 0..23 write output 0 ----
    int c2 = nck;                       // 24 <= c2 <= 96
    if (tid < c2) {
        int kk = ck[tid];
        int rk = 0;
        for (int j = 0; j < c2; ++j) rk += (ck[j] > kk);
        if (rk < K_) out_idx[(size_t)b * K_ + rk] = (float)(S_ - (kk & 1023)); // p+1
    }
}

extern "C" void kernel_launch(void* const* d_in, const int* in_sizes, int n_in,
                              void* d_out, int out_size, void* d_ws, size_t ws_size,
                              hipStream_t stream) {
    const float* x = (const float*)d_in[0];
    const int B = in_sizes[0] / (S_ * D_);

    float* out     = (float*)d_out;
    float* out_idx = out;                    // B*K_ (patch_idx, 1-based, as f32)
    float* out_cnt = out + (size_t)B * K_;   // B*S_ (count)

    mhv_kernel<<<dim3(B), dim3(NT), 0, stream>>>(x, out_idx, out_cnt);
}